// Round 2
// baseline (965.898 us; speedup 1.0000x reference)
//
#include <hip/hip_runtime.h>

// Problem constants (from reference setup_inputs)
#define B_ 8
#define T_ 2048
#define S_ 4096
#define D_ 128
#define N_ (B_*T_)          // 16384 total query rows
#define NTILE_ (S_/128)     // 32 col-tiles per row for softmax partials
#define NEG_INF_ (-1e9f)

// memory_lengths may arrive as int64 (jax x64) or int32. Values are in [1,4096],
// so if int64, p[1] (high word of elem 0) == 0; if int32, p[1] = len[1] >= 1.
__device__ __forceinline__ int load_len(const int* __restrict__ p, int b) {
    return (p[1] == 0) ? p[2*b] : p[b];
}

// ---------------------------------------------------------------------------
// C = A * B^T tile GEMM, K=128 fixed. Tile 128x128, 256 threads, 8x8 register
// tile. k-major LDS tiles (transpose on load). Column mapping per thread:
// cols = tx*4 + (j&3) + 64*(j>>2)  ->  all C writes are float4.
// MASK=true additionally masks cols >= len to -1e9 AND emits per-row-tile
// softmax partials (tile max, tile sum-exp) for later merge.
// ---------------------------------------------------------------------------
template<bool MASK>
__global__ __launch_bounds__(256) void gemm_nt_k128(
    const float* __restrict__ A, const float* __restrict__ Bmat,
    float* __restrict__ C, const int ldc, const long long bStride,
    const int* __restrict__ mlen,
    float* __restrict__ pmax, float* __restrict__ psum)
{
    __shared__ float At[16][128];
    __shared__ float Bt[16][128];
    const int t  = threadIdx.x;
    const int tx = t & 15, ty = t >> 4;
    const int col0 = blockIdx.x << 7;
    const int n0   = blockIdx.y << 7;
    const int b    = blockIdx.y >> 4;     // 16 row-tiles per batch (T/128)
    const float* Bb = Bmat + (long long)b * bStride;
    const int r_ld = t >> 1, kf = t & 1;

    float acc[8][8];
#pragma unroll
    for (int i = 0; i < 8; ++i)
#pragma unroll
        for (int j = 0; j < 8; ++j) acc[i][j] = 0.f;

    const float* Arow = &A[(long long)(n0 + r_ld) * 128];
    const float* Brow = &Bb[(long long)(col0 + r_ld) * 128];

    for (int k0 = 0; k0 < 128; k0 += 16) {
        __syncthreads();
#pragma unroll
        for (int u = 0; u < 2; ++u) {
            const int kk = kf*8 + u*4;
            const float4 va = *(const float4*)&Arow[k0 + kk];
            At[kk+0][r_ld] = va.x; At[kk+1][r_ld] = va.y;
            At[kk+2][r_ld] = va.z; At[kk+3][r_ld] = va.w;
            const float4 vb = *(const float4*)&Brow[k0 + kk];
            Bt[kk+0][r_ld] = vb.x; Bt[kk+1][r_ld] = vb.y;
            Bt[kk+2][r_ld] = vb.z; Bt[kk+3][r_ld] = vb.w;
        }
        __syncthreads();
#pragma unroll
        for (int kk = 0; kk < 16; ++kk) {
            float a[8], bv[8];
#pragma unroll
            for (int u = 0; u < 2; ++u) {
                const float4 v = *(const float4*)&At[kk][ty*8 + u*4];
                a[u*4+0]=v.x; a[u*4+1]=v.y; a[u*4+2]=v.z; a[u*4+3]=v.w;
                const float4 w = *(const float4*)&Bt[kk][tx*4 + u*64];
                bv[u*4+0]=w.x; bv[u*4+1]=w.y; bv[u*4+2]=w.z; bv[u*4+3]=w.w;
            }
#pragma unroll
            for (int i = 0; i < 8; ++i)
#pragma unroll
                for (int j = 0; j < 8; ++j)
                    acc[i][j] = fmaf(a[i], bv[j], acc[i][j]);
        }
    }

    if (MASK) {
        const int len = load_len(mlen, b);
#pragma unroll
        for (int i = 0; i < 8; ++i) {
            const int row = n0 + ty*8 + i;
            float* Crow = &C[(long long)row * ldc + col0];
            float m = -3.4e38f;
#pragma unroll
            for (int j = 0; j < 8; ++j) {
                const int cl = tx*4 + (j&3) + ((j>>2)<<6);
                float v = acc[i][j];
                if (col0 + cl >= len) v = NEG_INF_;
                acc[i][j] = v;
                m = fmaxf(m, v);
            }
            float4 w0, w1;
            w0.x=acc[i][0]; w0.y=acc[i][1]; w0.z=acc[i][2]; w0.w=acc[i][3];
            w1.x=acc[i][4]; w1.y=acc[i][5]; w1.z=acc[i][6]; w1.w=acc[i][7];
            *(float4*)&Crow[tx*4]      = w0;
            *(float4*)&Crow[tx*4 + 64] = w1;
            // per-row-tile softmax partials across the 16 tx lanes
#pragma unroll
            for (int off = 1; off < 16; off <<= 1) m = fmaxf(m, __shfl_xor(m, off, 64));
            float s = 0.f;
#pragma unroll
            for (int j = 0; j < 8; ++j) s += __expf(acc[i][j] - m);
#pragma unroll
            for (int off = 1; off < 16; off <<= 1) s += __shfl_xor(s, off, 64);
            if (tx == 0) {
                pmax[(long long)blockIdx.x * N_ + row] = m;
                psum[(long long)blockIdx.x * N_ + row] = s;
            }
        }
    } else {
#pragma unroll
        for (int i = 0; i < 8; ++i) {
            float* Crow = &C[(long long)(n0 + ty*8 + i) * ldc + col0];
            float4 w0, w1;
            w0.x=acc[i][0]; w0.y=acc[i][1]; w0.z=acc[i][2]; w0.w=acc[i][3];
            w1.x=acc[i][4]; w1.y=acc[i][5]; w1.z=acc[i][6]; w1.w=acc[i][7];
            *(float4*)&Crow[tx*4]      = w0;
            *(float4*)&Crow[tx*4 + 64] = w1;
        }
    }
}

// ---------------------------------------------------------------------------
// Merge per-tile softmax partials: M = max_i m_i; S = sum_i s_i*exp(m_i-M).
// One thread per row; reads are [tile][row] -> coalesced. 4 MB total.
// ---------------------------------------------------------------------------
__global__ __launch_bounds__(256) void merge_stats(
    const float* __restrict__ pmax, const float* __restrict__ psum,
    float* __restrict__ rmax, float* __restrict__ rrinv)
{
    const int r = blockIdx.x * 256 + threadIdx.x;
    float pm[NTILE_];
    float M = -3.4e38f;
#pragma unroll
    for (int i = 0; i < NTILE_; ++i) {
        pm[i] = pmax[(long long)i * N_ + r];
        M = fmaxf(M, pm[i]);
    }
    float S = 0.f;
#pragma unroll
    for (int i = 0; i < NTILE_; ++i)
        S += psum[(long long)i * N_ + r] * __expf(pm[i] - M);
    rmax[r]  = M;
    rrinv[r] = 1.0f / S;
}

// ---------------------------------------------------------------------------
// Fused: align -> p (write align_vectors) and partial c += p @ mb.
// Block: 128 rows x (S/split) cols, staged in 32-s chunks via LDS (33.8 KB).
// grid = (split, 128). Masked lanes: exp(-1e9 - M) == 0 -> av = 0 exactly.
// ---------------------------------------------------------------------------
__global__ __launch_bounds__(256) void av_cpart(
    const float* __restrict__ al, const float* __restrict__ mb,
    const float* __restrict__ rmax, const float* __restrict__ rrinv,
    float* __restrict__ av, float* __restrict__ cpart, const int sChunks)
{
    __shared__ float Pl[32][132];   // p chunk, [s][row] (transposed)
    __shared__ float Ml[32][132];   // mb chunk, [s][k]
    const int n0 = blockIdx.y << 7;
    const int b  = blockIdx.y >> 4;
    const int t  = threadIdx.x;
    const int tx = t & 15, ty = t >> 4;
    const int r_ld = t >> 1, sf = t & 1;   // align/av staging: 2 threads/row
    const int s_m  = t >> 3, kq8 = t & 7;  // mb staging: 8 threads/s-row

    const float mM = rmax[n0 + r_ld];
    const float rR = rrinv[n0 + r_ld];

    float acc[8][8];
#pragma unroll
    for (int i = 0; i < 8; ++i)
#pragma unroll
        for (int j = 0; j < 8; ++j) acc[i][j] = 0.f;

    const int ch0 = blockIdx.x * sChunks;
    for (int ch = 0; ch < sChunks; ++ch) {
        const int s0 = (ch0 + ch) << 5;
        __syncthreads();
#pragma unroll
        for (int f = 0; f < 4; ++f) {
            const int sl = sf*16 + f*4;
            const long long g = (long long)(n0 + r_ld) * S_ + s0 + sl;
            const float4 vv = *(const float4*)&al[g];
            float4 p;
            p.x = __expf(vv.x - mM) * rR;
            p.y = __expf(vv.y - mM) * rR;
            p.z = __expf(vv.z - mM) * rR;
            p.w = __expf(vv.w - mM) * rR;
            *(float4*)&av[g] = p;
            Pl[sl+0][r_ld] = p.x; Pl[sl+1][r_ld] = p.y;
            Pl[sl+2][r_ld] = p.z; Pl[sl+3][r_ld] = p.w;
        }
#pragma unroll
        for (int f = 0; f < 4; ++f) {
            const int k = kq8*16 + f*4;
            *(float4*)&Ml[s_m][k] =
                *(const float4*)&mb[((long long)b*S_ + s0 + s_m)*128 + k];
        }
        __syncthreads();
#pragma unroll 2
        for (int s = 0; s < 32; ++s) {
            float a[8], bv[8];
#pragma unroll
            for (int u = 0; u < 2; ++u) {
                const float4 v = *(const float4*)&Pl[s][ty*8 + u*4];
                a[u*4+0]=v.x; a[u*4+1]=v.y; a[u*4+2]=v.z; a[u*4+3]=v.w;
                const float4 w = *(const float4*)&Ml[s][tx*4 + u*64];
                bv[u*4+0]=w.x; bv[u*4+1]=w.y; bv[u*4+2]=w.z; bv[u*4+3]=w.w;
            }
#pragma unroll
            for (int i = 0; i < 8; ++i)
#pragma unroll
                for (int j = 0; j < 8; ++j)
                    acc[i][j] = fmaf(a[i], bv[j], acc[i][j]);
        }
    }

    float* cp = cpart + (long long)blockIdx.x * N_ * 128;
#pragma unroll
    for (int i = 0; i < 8; ++i) {
        const long long ro = (long long)(n0 + ty*8 + i) * 128;
        float4 w0, w1;
        w0.x=acc[i][0]; w0.y=acc[i][1]; w0.z=acc[i][2]; w0.w=acc[i][3];
        w1.x=acc[i][4]; w1.y=acc[i][5]; w1.z=acc[i][6]; w1.w=acc[i][7];
        *(float4*)&cp[ro + tx*4]      = w0;
        *(float4*)&cp[ro + tx*4 + 64] = w1;
    }
}

// ---------------------------------------------------------------------------
// Combine partial c, then attn_h = tanh([c, query] @ W_out^T). 32 rows/block,
// 512 blocks. LDS reads in the dot loop are row-uniform broadcasts (free).
// Safe when cpart aliases attn (block reads only its own rows, then writes).
// ---------------------------------------------------------------------------
__global__ __launch_bounds__(256) void combine_proj(
    const float* __restrict__ cpart, const int nSplit,
    const float* __restrict__ query, const float* __restrict__ Wout,
    float* __restrict__ attn)
{
    __shared__ float Cl[32][132];
    __shared__ float Ql[32][132];
    const int n0 = blockIdx.x << 5;
    const int t = threadIdx.x;
    const int r = t >> 3, kq = t & 7;
#pragma unroll
    for (int f = 0; f < 4; ++f) {
        const int k = kq*16 + f*4;
        const long long idx = (long long)(n0 + r) * 128 + k;
        float4 s4 = *(const float4*)&cpart[idx];
        for (int p = 1; p < nSplit; ++p) {
            const float4 v = *(const float4*)&cpart[(long long)p * N_ * 128 + idx];
            s4.x += v.x; s4.y += v.y; s4.z += v.z; s4.w += v.w;
        }
        *(float4*)&Cl[r][k] = s4;
        *(float4*)&Ql[r][k] = *(const float4*)&query[idx];
    }
    __syncthreads();

    const int j = t & 127, rh = t >> 7;    // rh in {0,1}: 16 rows each
    float acc2[16];
#pragma unroll
    for (int rr = 0; rr < 16; ++rr) acc2[rr] = 0.f;
    const float4* Wrow = (const float4*)&Wout[j * 256];

    for (int k4 = 0; k4 < 32; ++k4) {
        const float4 w = Wrow[k4];
#pragma unroll
        for (int rr = 0; rr < 16; ++rr) {
            const float4 c4 = *(const float4*)&Cl[rh*16 + rr][k4*4];
            acc2[rr] = fmaf(c4.x, w.x, fmaf(c4.y, w.y, fmaf(c4.z, w.z, fmaf(c4.w, w.w, acc2[rr]))));
        }
    }
    for (int k4 = 0; k4 < 32; ++k4) {
        const float4 w = Wrow[32 + k4];
#pragma unroll
        for (int rr = 0; rr < 16; ++rr) {
            const float4 q4 = *(const float4*)&Ql[rh*16 + rr][k4*4];
            acc2[rr] = fmaf(q4.x, w.x, fmaf(q4.y, w.y, fmaf(q4.z, w.z, fmaf(q4.w, w.w, acc2[rr]))));
        }
    }
#pragma unroll
    for (int rr = 0; rr < 16; ++rr)
        attn[(long long)(n0 + rh*16 + rr) * 128 + j] = tanhf(acc2[rr]);
}

// ---------------------------------------------------------------------------
extern "C" void kernel_launch(void* const* d_in, const int* in_sizes, int n_in,
                              void* d_out, int out_size, void* d_ws, size_t ws_size,
                              hipStream_t stream)
{
    const float* query = (const float*)d_in[0];   // [B][T][128]
    const float* mb    = (const float*)d_in[1];   // [B][S][128]
    const int*   mlen  = (const int*)d_in[2];     // [B] (int32 or int64)
    const float* Win   = (const float*)d_in[3];   // [128][128]
    const float* Wout  = (const float*)d_in[4];   // [128][256]

    float* attn  = (float*)d_out;                       // [N][128]
    float* av    = attn + (size_t)N_ * D_;              // [N][S]
    float* align = av   + (size_t)N_ * S_;              // [N][S]

    const size_t statsB = (size_t)2 * N_ * 4;           // 128 KB
    const size_t partB  = (size_t)2 * NTILE_ * N_ * 4;  // 4 MB (pmax+psum)
    const size_t matB   = (size_t)N_ * D_ * 4;          // 8 MB

    // Deterministic split selection (graph-safe).
    int split = 0;
    if      (ws_size >= statsB + partB + matB + 8*matB) split = 8;
    else if (ws_size >= statsB + partB + matB + 4*matB) split = 4;
    else if (ws_size >= statsB + partB + matB + 2*matB) split = 2;
    else if (ws_size >= statsB + partB + matB + 1*matB) split = 1;

    char* w = (char*)d_ws;
    float* rmax  = (float*)w;
    float* rrinv = rmax + N_;
    float *pmax, *psum, *cpart, *ht;
    int nSplit;
    if (split > 0) {
        pmax  = (float*)(w + statsB);
        psum  = pmax + (size_t)NTILE_ * N_;
        cpart = (float*)(w + statsB + partB);
        ht    = cpart + (size_t)split * N_ * D_;
        nSplit = split;
    } else {
        // Minimal-ws fallback: partials+ht live in the (not-yet-written) av
        // region; cpart aliases attn (written only after K5 reads it).
        pmax  = av;
        psum  = av + (size_t)NTILE_ * N_;
        ht    = av + (size_t)2 * NTILE_ * N_;
        cpart = attn;
        nSplit = 1;
    }

    // K1: h_t = query @ W_in^T
    gemm_nt_k128<false><<<dim3(1, 128), 256, 0, stream>>>(
        query, Win, ht, 128, 0LL, nullptr, nullptr, nullptr);
    // K2: align = h_t @ mb^T (masked) + per-tile softmax partials
    gemm_nt_k128<true><<<dim3(S_/128, 128), 256, 0, stream>>>(
        ht, mb, align, S_, (long long)S_ * D_, mlen, pmax, psum);
    // K3: merge partials -> rowmax, 1/rowsum
    merge_stats<<<N_/256, 256, 0, stream>>>(pmax, psum, rmax, rrinv);
    // K4: align_vectors + partial c
    av_cpart<<<dim3(nSplit, 128), 256, 0, stream>>>(
        align, mb, rmax, rrinv, av, cpart, (S_/32) / nSplit);
    // K5: combine c, output projection + tanh
    combine_proj<<<N_/32, 256, 0, stream>>>(cpart, nSplit, query, Wout, attn);
}

// Round 6
// 808.560 us; speedup vs baseline: 1.1946x; 1.1946x over previous
//
#include <hip/hip_runtime.h>

// Problem constants (from reference setup_inputs)
#define B_ 8
#define T_ 2048
#define S_ 4096
#define D_ 128
#define N_ (B_*T_)          // 16384 total query rows
#define NTILE_ (S_/128)     // 32 col-tiles per row for softmax partials
#define NEG_INF_ (-1e9f)

typedef __attribute__((ext_vector_type(8))) short bf16x8;
typedef __attribute__((ext_vector_type(4))) float f32x4;

// memory_lengths may arrive as int64 (jax x64) or int32. Values in [1,4096]:
// if int64, p[1] (high word of elem 0) == 0; if int32, p[1] = len[1] >= 1.
__device__ __forceinline__ int load_len(const int* __restrict__ p, int b) {
    return (p[1] == 0) ? p[2*b] : p[b];
}

// bf16 round-to-nearest-even
__device__ __forceinline__ unsigned short f2bf(float x) {
    unsigned u = __float_as_uint(x);
    unsigned r = (u + 0x7fffu + ((u >> 16) & 1u)) >> 16;
    return (unsigned short)r;
}
__device__ __forceinline__ float bf2f(unsigned short h) {
    return __uint_as_float(((unsigned)h) << 16);
}
__device__ __forceinline__ unsigned pk2(unsigned short a, unsigned short b) {
    return (unsigned)a | ((unsigned)b << 16);
}

// ---------------------------------------------------------------------------
// K0: mb -> {mb_hi, mb_lo} (row-major [b][s][f]) and {mbT_hi, mbT_lo}
// (transposed [b][f][s]). Tile 64s x 64f via LDS.
// ---------------------------------------------------------------------------
__global__ __launch_bounds__(256) void prep_mb(
    const float* __restrict__ mb,
    unsigned short* __restrict__ mbh, unsigned short* __restrict__ mbl,
    unsigned short* __restrict__ mbth, unsigned short* __restrict__ mbtl)
{
    __shared__ float tile[64][65];
    const int b = blockIdx.z, f0 = blockIdx.y << 6, s0 = blockIdx.x << 6;
    const int t = threadIdx.x;
#pragma unroll
    for (int i = 0; i < 4; ++i) {
        const int c = t + (i << 8);
        const int s = c >> 4, q = c & 15;
        const long long ga = ((long long)(b*S_ + s0 + s)) * 128 + f0 + q*4;
        const float4 v = *(const float4*)&mb[ga];
        tile[s][q*4+0] = v.x; tile[s][q*4+1] = v.y;
        tile[s][q*4+2] = v.z; tile[s][q*4+3] = v.w;
        unsigned short h0=f2bf(v.x), h1=f2bf(v.y), h2=f2bf(v.z), h3=f2bf(v.w);
        uint2 ph; ph.x = pk2(h0,h1); ph.y = pk2(h2,h3);
        *(uint2*)&mbh[ga] = ph;
        uint2 pl; pl.x = pk2(f2bf(v.x - bf2f(h0)), f2bf(v.y - bf2f(h1)));
        pl.y = pk2(f2bf(v.z - bf2f(h2)), f2bf(v.w - bf2f(h3)));
        *(uint2*)&mbl[ga] = pl;
    }
    __syncthreads();
    // transposed writes: thread -> feature f = t>>2, s-range (t&3)*16..+16
    const int f = t >> 2, q = t & 3;
    unsigned short h[16], l[16];
#pragma unroll
    for (int ss = 0; ss < 16; ++ss) {
        const float v = tile[q*16 + ss][f];
        h[ss] = f2bf(v);
        l[ss] = f2bf(v - bf2f(h[ss]));
    }
    const long long go = ((long long)(b*128 + f0 + f)) * S_ + s0 + q*16;
    uint4 w0, w1;
    w0.x=pk2(h[0],h[1]);  w0.y=pk2(h[2],h[3]);  w0.z=pk2(h[4],h[5]);  w0.w=pk2(h[6],h[7]);
    w1.x=pk2(h[8],h[9]);  w1.y=pk2(h[10],h[11]);w1.z=pk2(h[12],h[13]);w1.w=pk2(h[14],h[15]);
    *(uint4*)&mbth[go] = w0; *(uint4*)&mbth[go+8] = w1;
    w0.x=pk2(l[0],l[1]);  w0.y=pk2(l[2],l[3]);  w0.z=pk2(l[4],l[5]);  w0.w=pk2(l[6],l[7]);
    w1.x=pk2(l[8],l[9]);  w1.y=pk2(l[10],l[11]);w1.z=pk2(l[12],l[13]);w1.w=pk2(l[14],l[15]);
    *(uint4*)&mbtl[go] = w0; *(uint4*)&mbtl[go+8] = w1;
}

// ---------------------------------------------------------------------------
// K1: h_t = query @ W_in^T (fp32, small: 0.5 GF).
// ---------------------------------------------------------------------------
__global__ __launch_bounds__(256) void ht_gemm(
    const float* __restrict__ A, const float* __restrict__ Bmat,
    float* __restrict__ C)
{
    __shared__ float At[16][128];
    __shared__ float Bt[16][128];
    const int t  = threadIdx.x;
    const int tx = t & 15, ty = t >> 4;
    const int n0 = blockIdx.y << 7;
    const int r_ld = t >> 1, kf = t & 1;

    float acc[8][8];
#pragma unroll
    for (int i = 0; i < 8; ++i)
#pragma unroll
        for (int j = 0; j < 8; ++j) acc[i][j] = 0.f;

    const float* Arow = &A[(long long)(n0 + r_ld) * 128];
    const float* Brow = &Bmat[(long long)r_ld * 128];

    for (int k0 = 0; k0 < 128; k0 += 16) {
        __syncthreads();
#pragma unroll
        for (int u = 0; u < 2; ++u) {
            const int kk = kf*8 + u*4;
            const float4 va = *(const float4*)&Arow[k0 + kk];
            At[kk+0][r_ld] = va.x; At[kk+1][r_ld] = va.y;
            At[kk+2][r_ld] = va.z; At[kk+3][r_ld] = va.w;
            const float4 vb = *(const float4*)&Brow[k0 + kk];
            Bt[kk+0][r_ld] = vb.x; Bt[kk+1][r_ld] = vb.y;
            Bt[kk+2][r_ld] = vb.z; Bt[kk+3][r_ld] = vb.w;
        }
        __syncthreads();
#pragma unroll
        for (int kk = 0; kk < 16; ++kk) {
            float a[8], bv[8];
#pragma unroll
            for (int u = 0; u < 2; ++u) {
                const float4 v = *(const float4*)&At[kk][ty*8 + u*4];
                a[u*4+0]=v.x; a[u*4+1]=v.y; a[u*4+2]=v.z; a[u*4+3]=v.w;
                const float4 w = *(const float4*)&Bt[kk][tx*4 + u*64];
                bv[u*4+0]=w.x; bv[u*4+1]=w.y; bv[u*4+2]=w.z; bv[u*4+3]=w.w;
            }
#pragma unroll
            for (int i = 0; i < 8; ++i)
#pragma unroll
                for (int j = 0; j < 8; ++j)
                    acc[i][j] = fmaf(a[i], bv[j], acc[i][j]);
        }
    }
#pragma unroll
    for (int i = 0; i < 8; ++i) {
        float* Crow = &C[(long long)(n0 + ty*8 + i) * 128];
        float4 w0, w1;
        w0.x=acc[i][0]; w0.y=acc[i][1]; w0.z=acc[i][2]; w0.w=acc[i][3];
        w1.x=acc[i][4]; w1.y=acc[i][5]; w1.z=acc[i][6]; w1.w=acc[i][7];
        *(float4*)&Crow[tx*4]      = w0;
        *(float4*)&Crow[tx*4 + 64] = w1;
    }
}

// K1b: split fp32 array into bf16 hi/lo
__global__ __launch_bounds__(256) void split_bf16(
    const float* __restrict__ in, unsigned short* __restrict__ hi,
    unsigned short* __restrict__ lo, int n4)
{
    const int i = blockIdx.x * 256 + threadIdx.x;
    if (i >= n4) return;
    const float4 v = *(const float4*)&in[i*4];
    unsigned short h0=f2bf(v.x), h1=f2bf(v.y), h2=f2bf(v.z), h3=f2bf(v.w);
    uint2 ph; ph.x = pk2(h0,h1); ph.y = pk2(h2,h3);
    *(uint2*)&hi[i*4] = ph;
    uint2 pl; pl.x = pk2(f2bf(v.x-bf2f(h0)), f2bf(v.y-bf2f(h1)));
    pl.y = pk2(f2bf(v.z-bf2f(h2)), f2bf(v.w-bf2f(h3)));
    *(uint2*)&lo[i*4] = pl;
}

// ---------------------------------------------------------------------------
// K2: align = h_t @ mb^T via split-bf16 MFMA (3-term). 128x128 tile/block,
// 4 waves (2x2), each wave 64x64 via 4x4 16x16x32 MFMA tiles. Masks cols>=len
// to -1e9 and emits per-tile softmax partials. LDS pitch 40 shorts (80 B).
// Fully-masked tiles (c0 >= len, block-uniform) take a store-only fast path.
// ---------------------------------------------------------------------------
__global__ __launch_bounds__(256) void qk_mfma(
    const unsigned short* __restrict__ hth, const unsigned short* __restrict__ htl,
    const unsigned short* __restrict__ mbh, const unsigned short* __restrict__ mbl,
    float* __restrict__ alignO, const int* __restrict__ mlen,
    float* __restrict__ pmax, float* __restrict__ psum)
{
    __shared__ __align__(16) unsigned short Ah[128*40], Al[128*40];
    __shared__ __align__(16) unsigned short Bh[128*40], Bl[128*40];
    __shared__ float sm[2][128], ss[2][128];
    const int t = threadIdx.x, l = t & 63, w = t >> 6;
    const int wm = w >> 1, wn = w & 1, g = l >> 4, lr = l & 15;
    const int c0 = blockIdx.x << 7, n0 = blockIdx.y << 7;
    const int b  = blockIdx.y >> 4;
    const int len = load_len(mlen, b);

    if (c0 >= len) {
        // Whole tile masked: align=-1e9; partials merge to exactly 0
        // (psum*exp(-1e9-M) underflows; every row has a valid tile 0).
        const int r = t >> 1, half = (t & 1) << 6;
        float4 neg; neg.x = neg.y = neg.z = neg.w = NEG_INF_;
        float* Crow = &alignO[(long long)(n0 + r) * S_ + c0 + half];
#pragma unroll
        for (int q = 0; q < 16; ++q) *(float4*)&Crow[q*4] = neg;
        if (t < 128) {
            pmax[(long long)blockIdx.x * N_ + n0 + t] = NEG_INF_;
            psum[(long long)blockIdx.x * N_ + n0 + t] = 128.f;
        }
        return;
    }

    f32x4 acc[4][4];
#pragma unroll
    for (int mt = 0; mt < 4; ++mt)
#pragma unroll
        for (int nt = 0; nt < 4; ++nt) acc[mt][nt] = (f32x4)0.f;

    for (int k0 = 0; k0 < 128; k0 += 32) {
        __syncthreads();
#pragma unroll
        for (int i = 0; i < 2; ++i) {
            const int c = t + (i << 8);
            const int row = c >> 2, sl = c & 3;
            const int go = (n0 + row)*128 + k0 + sl*8;
            *(uint4*)&Ah[row*40 + sl*8] = *(const uint4*)&hth[go];
            *(uint4*)&Al[row*40 + sl*8] = *(const uint4*)&htl[go];
            const long long gb = ((long long)b*S_ + c0 + row)*128 + k0 + sl*8;
            *(uint4*)&Bh[row*40 + sl*8] = *(const uint4*)&mbh[gb];
            *(uint4*)&Bl[row*40 + sl*8] = *(const uint4*)&mbl[gb];
        }
        __syncthreads();
        bf16x8 ah[4], al[4];
#pragma unroll
        for (int mt = 0; mt < 4; ++mt) {
            const int r = wm*64 + mt*16 + lr;
            ah[mt] = *(const bf16x8*)&Ah[r*40 + g*8];
            al[mt] = *(const bf16x8*)&Al[r*40 + g*8];
        }
#pragma unroll
        for (int nt = 0; nt < 4; ++nt) {
            const int cc = wn*64 + nt*16 + lr;
            const bf16x8 bh = *(const bf16x8*)&Bh[cc*40 + g*8];
            const bf16x8 bl = *(const bf16x8*)&Bl[cc*40 + g*8];
#pragma unroll
            for (int mt = 0; mt < 4; ++mt) {
                acc[mt][nt] = __builtin_amdgcn_mfma_f32_16x16x32_bf16(ah[mt], bh, acc[mt][nt], 0, 0, 0);
                acc[mt][nt] = __builtin_amdgcn_mfma_f32_16x16x32_bf16(ah[mt], bl, acc[mt][nt], 0, 0, 0);
                acc[mt][nt] = __builtin_amdgcn_mfma_f32_16x16x32_bf16(al[mt], bh, acc[mt][nt], 0, 0, 0);
            }
        }
    }

    // mask (straddle tile)
#pragma unroll
    for (int nt = 0; nt < 4; ++nt) {
        const int col = c0 + wn*64 + nt*16 + lr;
        if (col >= len) {
#pragma unroll
            for (int mt = 0; mt < 4; ++mt)
#pragma unroll
                for (int j = 0; j < 4; ++j) acc[mt][nt][j] = NEG_INF_;
        }
    }
    // store + per-(wave-row) stats
#pragma unroll
    for (int mt = 0; mt < 4; ++mt) {
        float m[4] = {-3.4e38f, -3.4e38f, -3.4e38f, -3.4e38f};
#pragma unroll
        for (int nt = 0; nt < 4; ++nt)
#pragma unroll
            for (int j = 0; j < 4; ++j) m[j] = fmaxf(m[j], acc[mt][nt][j]);
#pragma unroll
        for (int j = 0; j < 4; ++j)
#pragma unroll
            for (int off = 1; off < 16; off <<= 1)
                m[j] = fmaxf(m[j], __shfl_xor(m[j], off, 64));
        float s[4] = {0.f, 0.f, 0.f, 0.f};
#pragma unroll
        for (int nt = 0; nt < 4; ++nt)
#pragma unroll
            for (int j = 0; j < 4; ++j) s[j] += __expf(acc[mt][nt][j] - m[j]);
#pragma unroll
        for (int j = 0; j < 4; ++j)
#pragma unroll
            for (int off = 1; off < 16; off <<= 1)
                s[j] += __shfl_xor(s[j], off, 64);
        if (lr == 0) {
#pragma unroll
            for (int j = 0; j < 4; ++j) {
                const int row = wm*64 + mt*16 + 4*g + j;
                sm[wn][row] = m[j]; ss[wn][row] = s[j];
            }
        }
#pragma unroll
        for (int nt = 0; nt < 4; ++nt) {
            const int col = c0 + wn*64 + nt*16 + lr;
#pragma unroll
            for (int j = 0; j < 4; ++j)
                alignO[(long long)(n0 + wm*64 + mt*16 + 4*g + j)*S_ + col] = acc[mt][nt][j];
        }
    }
    __syncthreads();
    if (t < 128) {
        const float m0 = sm[0][t], m1 = sm[1][t];
        const float M = fmaxf(m0, m1);
        const float Sv = ss[0][t]*__expf(m0 - M) + ss[1][t]*__expf(m1 - M);
        pmax[(long long)blockIdx.x * N_ + n0 + t] = M;
        psum[(long long)blockIdx.x * N_ + n0 + t] = Sv;
    }
}

// ---------------------------------------------------------------------------
// K3: merge per-tile softmax partials.
// ---------------------------------------------------------------------------
__global__ __launch_bounds__(256) void merge_stats(
    const float* __restrict__ pmax, const float* __restrict__ psum,
    float* __restrict__ rmax, float* __restrict__ rrinv)
{
    const int r = blockIdx.x * 256 + threadIdx.x;
    float pm[NTILE_];
    float M = -3.4e38f;
#pragma unroll
    for (int i = 0; i < NTILE_; ++i) {
        pm[i] = pmax[(long long)i * N_ + r];
        M = fmaxf(M, pm[i]);
    }
    float S = 0.f;
#pragma unroll
    for (int i = 0; i < NTILE_; ++i)
        S += psum[(long long)i * N_ + r] * __expf(pm[i] - M);
    rmax[r]  = M;
    rrinv[r] = 1.0f / S;
}

// ---------------------------------------------------------------------------
// K4: read align, p = exp(a-M)*R, write align_vectors; c += p @ mb via
// split-bf16 MFMA (B-operand from transposed mbT). 128 rows x (S/split) s
// per block, s-chunks of 32 (one MFMA k-step). grid (split, 128).
// Chunks entirely past len (block-uniform) take a zero-store fast path.
// ---------------------------------------------------------------------------
__global__ __launch_bounds__(256) void pv_mfma(
    const float* __restrict__ alignI,
    const unsigned short* __restrict__ mbth, const unsigned short* __restrict__ mbtl,
    const float* __restrict__ rmax, const float* __restrict__ rrinv,
    const int* __restrict__ mlen,
    float* __restrict__ av, float* __restrict__ cpart, const int sChunks)
{
    __shared__ __align__(16) unsigned short Ph[128*40], Pl[128*40];
    __shared__ __align__(16) unsigned short Vh[128*40], Vl[128*40];
    const int t = threadIdx.x, l = t & 63, w = t >> 6;
    const int wm = w >> 1, wn = w & 1, g = l >> 4, lr = l & 15;
    const int n0 = blockIdx.y << 7, b = blockIdx.y >> 4;
    const int r_st = t >> 1, hf = t & 1;
    const int len = load_len(mlen, b);
    const float M = rmax[n0 + r_st], R = rrinv[n0 + r_st];

    f32x4 acc[4][4];
#pragma unroll
    for (int mt = 0; mt < 4; ++mt)
#pragma unroll
        for (int nt = 0; nt < 4; ++nt) acc[mt][nt] = (f32x4)0.f;

    const int s00 = blockIdx.x * sChunks * 32;
    for (int ch = 0; ch < sChunks; ++ch) {
        const int s0 = s00 + (ch << 5);
        if (s0 >= len) {
            // masked chunk: av = 0 exactly; zero contribution to c.
            const long long ga = (long long)(n0 + r_st)*S_ + s0 + hf*16;
            float4 z; z.x = z.y = z.z = z.w = 0.f;
#pragma unroll
            for (int q = 0; q < 4; ++q) *(float4*)&av[ga + q*4] = z;
            continue;
        }
        __syncthreads();
        // stage p (and write av): thread owns 16 s of row r_st
        {
            unsigned short ph[16], pl[16];
            const long long ga = (long long)(n0 + r_st)*S_ + s0 + hf*16;
#pragma unroll
            for (int q = 0; q < 4; ++q) {
                const float4 v = *(const float4*)&alignI[ga + q*4];
                float4 p;
                p.x = __expf(v.x - M)*R; p.y = __expf(v.y - M)*R;
                p.z = __expf(v.z - M)*R; p.w = __expf(v.w - M)*R;
                *(float4*)&av[ga + q*4] = p;
                ph[q*4+0]=f2bf(p.x); pl[q*4+0]=f2bf(p.x - bf2f(ph[q*4+0]));
                ph[q*4+1]=f2bf(p.y); pl[q*4+1]=f2bf(p.y - bf2f(ph[q*4+1]));
                ph[q*4+2]=f2bf(p.z); pl[q*4+2]=f2bf(p.z - bf2f(ph[q*4+2]));
                ph[q*4+3]=f2bf(p.w); pl[q*4+3]=f2bf(p.w - bf2f(ph[q*4+3]));
            }
            uint4 w0, w1;
            w0.x=pk2(ph[0],ph[1]);  w0.y=pk2(ph[2],ph[3]);  w0.z=pk2(ph[4],ph[5]);  w0.w=pk2(ph[6],ph[7]);
            w1.x=pk2(ph[8],ph[9]);  w1.y=pk2(ph[10],ph[11]);w1.z=pk2(ph[12],ph[13]);w1.w=pk2(ph[14],ph[15]);
            *(uint4*)&Ph[r_st*40 + hf*16]     = w0;
            *(uint4*)&Ph[r_st*40 + hf*16 + 8] = w1;
            w0.x=pk2(pl[0],pl[1]);  w0.y=pk2(pl[2],pl[3]);  w0.z=pk2(pl[4],pl[5]);  w0.w=pk2(pl[6],pl[7]);
            w1.x=pk2(pl[8],pl[9]);  w1.y=pk2(pl[10],pl[11]);w1.z=pk2(pl[12],pl[13]);w1.w=pk2(pl[14],pl[15]);
            *(uint4*)&Pl[r_st*40 + hf*16]     = w0;
            *(uint4*)&Pl[r_st*40 + hf*16 + 8] = w1;
        }
        // stage V^T tile: [feat][32 s]
#pragma unroll
        for (int i = 0; i < 2; ++i) {
            const int c = t + (i << 8);
            const int f = c >> 2, sl = c & 3;
            const long long gv = ((long long)(b*128 + f))*S_ + s0 + sl*8;
            *(uint4*)&Vh[f*40 + sl*8] = *(const uint4*)&mbth[gv];
            *(uint4*)&Vl[f*40 + sl*8] = *(const uint4*)&mbtl[gv];
        }
        __syncthreads();
        bf16x8 ph[4], pl[4];
#pragma unroll
        for (int mt = 0; mt < 4; ++mt) {
            const int r = wm*64 + mt*16 + lr;
            ph[mt] = *(const bf16x8*)&Ph[r*40 + g*8];
            pl[mt] = *(const bf16x8*)&Pl[r*40 + g*8];
        }
#pragma unroll
        for (int nt = 0; nt < 4; ++nt) {
            const int f = wn*64 + nt*16 + lr;
            const bf16x8 vh = *(const bf16x8*)&Vh[f*40 + g*8];
            const bf16x8 vl = *(const bf16x8*)&Vl[f*40 + g*8];
#pragma unroll
            for (int mt = 0; mt < 4; ++mt) {
                acc[mt][nt] = __builtin_amdgcn_mfma_f32_16x16x32_bf16(ph[mt], vh, acc[mt][nt], 0, 0, 0);
                acc[mt][nt] = __builtin_amdgcn_mfma_f32_16x16x32_bf16(ph[mt], vl, acc[mt][nt], 0, 0, 0);
                acc[mt][nt] = __builtin_amdgcn_mfma_f32_16x16x32_bf16(pl[mt], vh, acc[mt][nt], 0, 0, 0);
            }
        }
    }

    float* cp = cpart + (long long)blockIdx.x * N_ * 128;
#pragma unroll
    for (int mt = 0; mt < 4; ++mt)
#pragma unroll
        for (int nt = 0; nt < 4; ++nt)
#pragma unroll
            for (int j = 0; j < 4; ++j)
                cp[(long long)(n0 + wm*64 + mt*16 + 4*g + j)*128 + wn*64 + nt*16 + lr]
                    = acc[mt][nt][j];
}

// ---------------------------------------------------------------------------
// K5: combine partial c, attn_h = tanh([c,q] @ W_out^T).
// ---------------------------------------------------------------------------
__global__ __launch_bounds__(256) void combine_proj(
    const float* __restrict__ cpart, const int nSplit,
    const float* __restrict__ query, const float* __restrict__ Wout,
    float* __restrict__ attn)
{
    __shared__ float Cl[32][132];
    __shared__ float Ql[32][132];
    const int n0 = blockIdx.x << 5;
    const int t = threadIdx.x;
    const int r = t >> 3, kq = t & 7;
#pragma unroll
    for (int f = 0; f < 4; ++f) {
        const int k = kq*16 + f*4;
        const long long idx = (long long)(n0 + r) * 128 + k;
        float4 s4 = *(const float4*)&cpart[idx];
        for (int p = 1; p < nSplit; ++p) {
            const float4 v = *(const float4*)&cpart[(long long)p * N_ * 128 + idx];
            s4.x += v.x; s4.y += v.y; s4.z += v.z; s4.w += v.w;
        }
        *(float4*)&Cl[r][k] = s4;
        *(float4*)&Ql[r][k] = *(const float4*)&query[idx];
    }
    __syncthreads();

    const int j = t & 127, rh = t >> 7;
    float acc2[16];
#pragma unroll
    for (int rr = 0; rr < 16; ++rr) acc2[rr] = 0.f;
    const float4* Wrow = (const float4*)&Wout[j * 256];

    for (int k4 = 0; k4 < 32; ++k4) {
        const float4 w = Wrow[k4];
#pragma unroll
        for (int rr = 0; rr < 16; ++rr) {
            const float4 c4 = *(const float4*)&Cl[rh*16 + rr][k4*4];
            acc2[rr] = fmaf(c4.x, w.x, fmaf(c4.y, w.y, fmaf(c4.z, w.z, fmaf(c4.w, w.w, acc2[rr]))));
        }
    }
    for (int k4 = 0; k4 < 32; ++k4) {
        const float4 w = Wrow[32 + k4];
#pragma unroll
        for (int rr = 0; rr < 16; ++rr) {
            const float4 q4 = *(const float4*)&Ql[rh*16 + rr][k4*4];
            acc2[rr] = fmaf(q4.x, w.x, fmaf(q4.y, w.y, fmaf(q4.z, w.z, fmaf(q4.w, w.w, acc2[rr]))));
        }
    }
#pragma unroll
    for (int rr = 0; rr < 16; ++rr)
        attn[(long long)(n0 + rh*16 + rr) * 128 + j] = tanhf(acc2[rr]);
}

// ---------------------------------------------------------------------------
extern "C" void kernel_launch(void* const* d_in, const int* in_sizes, int n_in,
                              void* d_out, int out_size, void* d_ws, size_t ws_size,
                              hipStream_t stream)
{
    const float* query = (const float*)d_in[0];   // [B][T][128]
    const float* mb    = (const float*)d_in[1];   // [B][S][128]
    const int*   mlen  = (const int*)d_in[2];     // [B]
    const float* Win   = (const float*)d_in[3];   // [128][128]
    const float* Wout  = (const float*)d_in[4];   // [128][256]

    float* attn  = (float*)d_out;
    float* av    = attn + (size_t)N_ * D_;
    float* align = av   + (size_t)N_ * S_;

    // workspace layout (ws observed ~2 GB; need ~117 MB at split=4)
    char* p = (char*)d_ws;
    float* rmax  = (float*)p;                 p += (size_t)N_ * 4;
    float* rrinv = (float*)p;                 p += (size_t)N_ * 4;
    float* pmax  = (float*)p;                 p += (size_t)NTILE_ * N_ * 4;
    float* psum  = (float*)p;                 p += (size_t)NTILE_ * N_ * 4;
    float* ht    = (float*)p;                 p += (size_t)N_ * D_ * 4;
    unsigned short* hth  = (unsigned short*)p; p += (size_t)N_ * D_ * 2;
    unsigned short* htl  = (unsigned short*)p; p += (size_t)N_ * D_ * 2;
    unsigned short* mbh  = (unsigned short*)p; p += (size_t)B_ * S_ * D_ * 2;
    unsigned short* mbl  = (unsigned short*)p; p += (size_t)B_ * S_ * D_ * 2;
    unsigned short* mbth = (unsigned short*)p; p += (size_t)B_ * S_ * D_ * 2;
    unsigned short* mbtl = (unsigned short*)p; p += (size_t)B_ * S_ * D_ * 2;
    const size_t usedBase = (size_t)(p - (char*)d_ws);
    const size_t matB = (size_t)N_ * D_ * 4;

    int split;
    float* cpart;
    if (ws_size >= usedBase + 4*matB)      { split = 4; cpart = (float*)p; }
    else if (ws_size >= usedBase + 2*matB) { split = 2; cpart = (float*)p; }
    else if (ws_size >= usedBase + matB)   { split = 1; cpart = (float*)p; }
    else                                   { split = 1; cpart = attn; } // K5 reads own rows then writes

    // K0: mb bf16 splits (row-major + transposed)
    prep_mb<<<dim3(S_/64, 2, B_), 256, 0, stream>>>(mb, mbh, mbl, mbth, mbtl);
    // K1: h_t fp32
    ht_gemm<<<dim3(1, N_/128), 256, 0, stream>>>(query, Win, ht);
    // K1b: h_t -> bf16 hi/lo
    split_bf16<<<(N_*D_/4)/256, 256, 0, stream>>>(ht, hth, htl, N_*D_/4);
    // K2: align (masked) + softmax partials
    qk_mfma<<<dim3(S_/128, N_/128), 256, 0, stream>>>(
        hth, htl, mbh, mbl, align, mlen, pmax, psum);
    // K3: merge stats
    merge_stats<<<N_/256, 256, 0, stream>>>(pmax, psum, rmax, rrinv);
    // K4: align_vectors + partial c
    pv_mfma<<<dim3(split, N_/128), 256, 0, stream>>>(
        align, mbth, mbtl, rmax, rrinv, mlen, av, cpart, (S_/32)/split);
    // K5: combine + output projection
    combine_proj<<<N_/32, 256, 0, stream>>>(cpart, split, query, Wout, attn);
}

// Round 8
// 794.260 us; speedup vs baseline: 1.2161x; 1.0180x over previous
//
#include <hip/hip_runtime.h>

// Problem constants (from reference setup_inputs)
#define B_ 8
#define T_ 2048
#define S_ 4096
#define D_ 128
#define N_ (B_*T_)          // 16384 total query rows
#define NTILE_ (S_/128)     // 32 col-tiles per row for softmax partials
#define NEG_INF_ (-1e9f)

typedef __attribute__((ext_vector_type(8))) short bf16x8;
typedef __attribute__((ext_vector_type(4))) float f32x4;

// memory_lengths may arrive as int64 (jax x64) or int32. Values in [1,4096]:
// if int64, p[1] (high word of elem 0) == 0; if int32, p[1] = len[1] >= 1.
__device__ __forceinline__ int load_len(const int* __restrict__ p, int b) {
    return (p[1] == 0) ? p[2*b] : p[b];
}

// bf16 round-to-nearest-even
__device__ __forceinline__ unsigned short f2bf(float x) {
    unsigned u = __float_as_uint(x);
    unsigned r = (u + 0x7fffu + ((u >> 16) & 1u)) >> 16;
    return (unsigned short)r;
}
__device__ __forceinline__ float bf2f(unsigned short h) {
    return __uint_as_float(((unsigned)h) << 16);
}
__device__ __forceinline__ unsigned pk2(unsigned short a, unsigned short b) {
    return (unsigned)a | ((unsigned)b << 16);
}

// ---------------------------------------------------------------------------
// K0: mb -> {mb_hi, mb_lo} (row-major, for qk 3-term) and mbT_hi
// (transposed [b][f][s], for pv 1-term). Tile 64s x 64f via LDS.
// ---------------------------------------------------------------------------
__global__ __launch_bounds__(256) void prep_mb(
    const float* __restrict__ mb,
    unsigned short* __restrict__ mbh, unsigned short* __restrict__ mbl,
    unsigned short* __restrict__ mbth)
{
    __shared__ float tile[64][65];
    const int b = blockIdx.z, f0 = blockIdx.y << 6, s0 = blockIdx.x << 6;
    const int t = threadIdx.x;
#pragma unroll
    for (int i = 0; i < 4; ++i) {
        const int c = t + (i << 8);
        const int s = c >> 4, q = c & 15;
        const long long ga = ((long long)(b*S_ + s0 + s)) * 128 + f0 + q*4;
        const float4 v = *(const float4*)&mb[ga];
        tile[s][q*4+0] = v.x; tile[s][q*4+1] = v.y;
        tile[s][q*4+2] = v.z; tile[s][q*4+3] = v.w;
        unsigned short h0=f2bf(v.x), h1=f2bf(v.y), h2=f2bf(v.z), h3=f2bf(v.w);
        uint2 ph; ph.x = pk2(h0,h1); ph.y = pk2(h2,h3);
        *(uint2*)&mbh[ga] = ph;
        uint2 pl; pl.x = pk2(f2bf(v.x - bf2f(h0)), f2bf(v.y - bf2f(h1)));
        pl.y = pk2(f2bf(v.z - bf2f(h2)), f2bf(v.w - bf2f(h3)));
        *(uint2*)&mbl[ga] = pl;
    }
    __syncthreads();
    // transposed hi writes: thread -> feature f = t>>2, s-range (t&3)*16..+16
    const int f = t >> 2, q = t & 3;
    unsigned short h[16];
#pragma unroll
    for (int ss = 0; ss < 16; ++ss) h[ss] = f2bf(tile[q*16 + ss][f]);
    const long long go = ((long long)(b*128 + f0 + f)) * S_ + s0 + q*16;
    uint4 w0, w1;
    w0.x=pk2(h[0],h[1]);  w0.y=pk2(h[2],h[3]);  w0.z=pk2(h[4],h[5]);  w0.w=pk2(h[6],h[7]);
    w1.x=pk2(h[8],h[9]);  w1.y=pk2(h[10],h[11]);w1.z=pk2(h[12],h[13]);w1.w=pk2(h[14],h[15]);
    *(uint4*)&mbth[go] = w0; *(uint4*)&mbth[go+8] = w1;
}

// ---------------------------------------------------------------------------
// K1: h_t = query @ W_in^T (fp32, small: 0.5 GF).
// ---------------------------------------------------------------------------
__global__ __launch_bounds__(256) void ht_gemm(
    const float* __restrict__ A, const float* __restrict__ Bmat,
    float* __restrict__ C)
{
    __shared__ float At[16][128];
    __shared__ float Bt[16][128];
    const int t  = threadIdx.x;
    const int tx = t & 15, ty = t >> 4;
    const int n0 = blockIdx.y << 7;
    const int r_ld = t >> 1, kf = t & 1;

    float acc[8][8];
#pragma unroll
    for (int i = 0; i < 8; ++i)
#pragma unroll
        for (int j = 0; j < 8; ++j) acc[i][j] = 0.f;

    const float* Arow = &A[(long long)(n0 + r_ld) * 128];
    const float* Brow = &Bmat[(long long)r_ld * 128];

    for (int k0 = 0; k0 < 128; k0 += 16) {
        __syncthreads();
#pragma unroll
        for (int u = 0; u < 2; ++u) {
            const int kk = kf*8 + u*4;
            const float4 va = *(const float4*)&Arow[k0 + kk];
            At[kk+0][r_ld] = va.x; At[kk+1][r_ld] = va.y;
            At[kk+2][r_ld] = va.z; At[kk+3][r_ld] = va.w;
            const float4 vb = *(const float4*)&Brow[k0 + kk];
            Bt[kk+0][r_ld] = vb.x; Bt[kk+1][r_ld] = vb.y;
            Bt[kk+2][r_ld] = vb.z; Bt[kk+3][r_ld] = vb.w;
        }
        __syncthreads();
#pragma unroll
        for (int kk = 0; kk < 16; ++kk) {
            float a[8], bv[8];
#pragma unroll
            for (int u = 0; u < 2; ++u) {
                const float4 v = *(const float4*)&At[kk][ty*8 + u*4];
                a[u*4+0]=v.x; a[u*4+1]=v.y; a[u*4+2]=v.z; a[u*4+3]=v.w;
                const float4 w = *(const float4*)&Bt[kk][tx*4 + u*64];
                bv[u*4+0]=w.x; bv[u*4+1]=w.y; bv[u*4+2]=w.z; bv[u*4+3]=w.w;
            }
#pragma unroll
            for (int i = 0; i < 8; ++i)
#pragma unroll
                for (int j = 0; j < 8; ++j)
                    acc[i][j] = fmaf(a[i], bv[j], acc[i][j]);
        }
    }
#pragma unroll
    for (int i = 0; i < 8; ++i) {
        float* Crow = &C[(long long)(n0 + ty*8 + i) * 128];
        float4 w0, w1;
        w0.x=acc[i][0]; w0.y=acc[i][1]; w0.z=acc[i][2]; w0.w=acc[i][3];
        w1.x=acc[i][4]; w1.y=acc[i][5]; w1.z=acc[i][6]; w1.w=acc[i][7];
        *(float4*)&Crow[tx*4]      = w0;
        *(float4*)&Crow[tx*4 + 64] = w1;
    }
}

// K1b: split fp32 array into bf16 hi/lo
__global__ __launch_bounds__(256) void split_bf16(
    const float* __restrict__ in, unsigned short* __restrict__ hi,
    unsigned short* __restrict__ lo, int n4)
{
    const int i = blockIdx.x * 256 + threadIdx.x;
    if (i >= n4) return;
    const float4 v = *(const float4*)&in[i*4];
    unsigned short h0=f2bf(v.x), h1=f2bf(v.y), h2=f2bf(v.z), h3=f2bf(v.w);
    uint2 ph; ph.x = pk2(h0,h1); ph.y = pk2(h2,h3);
    *(uint2*)&hi[i*4] = ph;
    uint2 pl; pl.x = pk2(f2bf(v.x-bf2f(h0)), f2bf(v.y-bf2f(h1)));
    pl.y = pk2(f2bf(v.z-bf2f(h2)), f2bf(v.w-bf2f(h3)));
    *(uint2*)&lo[i*4] = pl;
}

// ---------------------------------------------------------------------------
// K2: align = h_t @ mb^T via split-bf16 MFMA (3-term; align is an output at
// absmax risk, keep precision). 128x128 tile/block, 4 waves, 4x4 16x16x32
// tiles/wave. Fully-masked tiles: coalesced -1e9 store fast path.
// ---------------------------------------------------------------------------
__global__ __launch_bounds__(256) void qk_mfma(
    const unsigned short* __restrict__ hth, const unsigned short* __restrict__ htl,
    const unsigned short* __restrict__ mbh, const unsigned short* __restrict__ mbl,
    float* __restrict__ alignO, const int* __restrict__ mlen,
    float* __restrict__ pmax, float* __restrict__ psum)
{
    __shared__ __align__(16) unsigned short Ah[128*40], Al[128*40];
    __shared__ __align__(16) unsigned short Bh[128*40], Bl[128*40];
    __shared__ float sm[2][128], ss[2][128];
    const int t = threadIdx.x, l = t & 63, w = t >> 6;
    const int wm = w >> 1, wn = w & 1, g = l >> 4, lr = l & 15;
    const int c0 = blockIdx.x << 7, n0 = blockIdx.y << 7;
    const int b  = blockIdx.y >> 4;
    const int len = load_len(mlen, b);

    if (c0 >= len) {
        // Whole tile masked: coalesced -1e9 stores (contiguous 1 KB per
        // wave-instruction); partials merge to exactly 0 downstream.
        float4 neg; neg.x = neg.y = neg.z = neg.w = NEG_INF_;
#pragma unroll
        for (int i = 0; i < 16; ++i) {
            const int c = i*1024 + t*4;          // linear in 128x128 tile
            const int row = c >> 7, col = c & 127;
            *(float4*)&alignO[(long long)(n0 + row)*S_ + c0 + col] = neg;
        }
        if (t < 128) {
            pmax[(long long)blockIdx.x * N_ + n0 + t] = NEG_INF_;
            psum[(long long)blockIdx.x * N_ + n0 + t] = 128.f;
        }
        return;
    }

    f32x4 acc[4][4];
#pragma unroll
    for (int mt = 0; mt < 4; ++mt)
#pragma unroll
        for (int nt = 0; nt < 4; ++nt) acc[mt][nt] = (f32x4)0.f;

    for (int k0 = 0; k0 < 128; k0 += 32) {
        __syncthreads();
#pragma unroll
        for (int i = 0; i < 2; ++i) {
            const int c = t + (i << 8);
            const int row = c >> 2, sl = c & 3;
            const int go = (n0 + row)*128 + k0 + sl*8;
            *(uint4*)&Ah[row*40 + sl*8] = *(const uint4*)&hth[go];
            *(uint4*)&Al[row*40 + sl*8] = *(const uint4*)&htl[go];
            const long long gb = ((long long)b*S_ + c0 + row)*128 + k0 + sl*8;
            *(uint4*)&Bh[row*40 + sl*8] = *(const uint4*)&mbh[gb];
            *(uint4*)&Bl[row*40 + sl*8] = *(const uint4*)&mbl[gb];
        }
        __syncthreads();
        bf16x8 ah[4], al[4];
#pragma unroll
        for (int mt = 0; mt < 4; ++mt) {
            const int r = wm*64 + mt*16 + lr;
            ah[mt] = *(const bf16x8*)&Ah[r*40 + g*8];
            al[mt] = *(const bf16x8*)&Al[r*40 + g*8];
        }
#pragma unroll
        for (int nt = 0; nt < 4; ++nt) {
            const int cc = wn*64 + nt*16 + lr;
            const bf16x8 bh = *(const bf16x8*)&Bh[cc*40 + g*8];
            const bf16x8 bl = *(const bf16x8*)&Bl[cc*40 + g*8];
#pragma unroll
            for (int mt = 0; mt < 4; ++mt) {
                acc[mt][nt] = __builtin_amdgcn_mfma_f32_16x16x32_bf16(ah[mt], bh, acc[mt][nt], 0, 0, 0);
                acc[mt][nt] = __builtin_amdgcn_mfma_f32_16x16x32_bf16(ah[mt], bl, acc[mt][nt], 0, 0, 0);
                acc[mt][nt] = __builtin_amdgcn_mfma_f32_16x16x32_bf16(al[mt], bh, acc[mt][nt], 0, 0, 0);
            }
        }
    }

    // mask (straddle tile)
#pragma unroll
    for (int nt = 0; nt < 4; ++nt) {
        const int col = c0 + wn*64 + nt*16 + lr;
        if (col >= len) {
#pragma unroll
            for (int mt = 0; mt < 4; ++mt)
#pragma unroll
                for (int j = 0; j < 4; ++j) acc[mt][nt][j] = NEG_INF_;
        }
    }
    // store + per-(wave-row) stats
#pragma unroll
    for (int mt = 0; mt < 4; ++mt) {
        float m[4] = {-3.4e38f, -3.4e38f, -3.4e38f, -3.4e38f};
#pragma unroll
        for (int nt = 0; nt < 4; ++nt)
#pragma unroll
            for (int j = 0; j < 4; ++j) m[j] = fmaxf(m[j], acc[mt][nt][j]);
#pragma unroll
        for (int j = 0; j < 4; ++j)
#pragma unroll
            for (int off = 1; off < 16; off <<= 1)
                m[j] = fmaxf(m[j], __shfl_xor(m[j], off, 64));
        float s[4] = {0.f, 0.f, 0.f, 0.f};
#pragma unroll
        for (int nt = 0; nt < 4; ++nt)
#pragma unroll
            for (int j = 0; j < 4; ++j) s[j] += __expf(acc[mt][nt][j] - m[j]);
#pragma unroll
        for (int j = 0; j < 4; ++j)
#pragma unroll
            for (int off = 1; off < 16; off <<= 1)
                s[j] += __shfl_xor(s[j], off, 64);
        if (lr == 0) {
#pragma unroll
            for (int j = 0; j < 4; ++j) {
                const int row = wm*64 + mt*16 + 4*g + j;
                sm[wn][row] = m[j]; ss[wn][row] = s[j];
            }
        }
#pragma unroll
        for (int nt = 0; nt < 4; ++nt) {
            const int col = c0 + wn*64 + nt*16 + lr;
#pragma unroll
            for (int j = 0; j < 4; ++j)
                alignO[(long long)(n0 + wm*64 + mt*16 + 4*g + j)*S_ + col] = acc[mt][nt][j];
        }
    }
    __syncthreads();
    if (t < 128) {
        const float m0 = sm[0][t], m1 = sm[1][t];
        const float M = fmaxf(m0, m1);
        const float Sv = ss[0][t]*__expf(m0 - M) + ss[1][t]*__expf(m1 - M);
        pmax[(long long)blockIdx.x * N_ + n0 + t] = M;
        psum[(long long)blockIdx.x * N_ + n0 + t] = Sv;
    }
}

// ---------------------------------------------------------------------------
// K3: merge per-tile softmax partials.
// ---------------------------------------------------------------------------
__global__ __launch_bounds__(256) void merge_stats(
    const float* __restrict__ pmax, const float* __restrict__ psum,
    float* __restrict__ rmax, float* __restrict__ rrinv)
{
    const int r = blockIdx.x * 256 + threadIdx.x;
    float pm[NTILE_];
    float M = -3.4e38f;
#pragma unroll
    for (int i = 0; i < NTILE_; ++i) {
        pm[i] = pmax[(long long)i * N_ + r];
        M = fmaxf(M, pm[i]);
    }
    float S = 0.f;
#pragma unroll
    for (int i = 0; i < NTILE_; ++i)
        S += psum[(long long)i * N_ + r] * __expf(pm[i] - M);
    rmax[r]  = M;
    rrinv[r] = 1.0f / S;
}

// ---------------------------------------------------------------------------
// K4: read align, p = exp(a-M)*R, write align_vectors; c += p @ mb via
// SINGLE-term bf16 MFMA (p in [0,1]: lo-terms contribute ~2e-4 abs to c —
// negligible under tanh; av itself is computed/stored in fp32).
// 128 rows x (S/split) s per block, s-chunks of 32. grid (split, 128).
// ---------------------------------------------------------------------------
__global__ __launch_bounds__(256) void pv_mfma(
    const float* __restrict__ alignI,
    const unsigned short* __restrict__ mbth,
    const float* __restrict__ rmax, const float* __restrict__ rrinv,
    const int* __restrict__ mlen,
    float* __restrict__ av, float* __restrict__ cpart, const int sChunks)
{
    __shared__ __align__(16) unsigned short Ph[128*40];
    __shared__ __align__(16) unsigned short Vh[128*40];
    const int t = threadIdx.x, l = t & 63, w = t >> 6;
    const int wm = w >> 1, wn = w & 1, g = l >> 4, lr = l & 15;
    const int n0 = blockIdx.y << 7, b = blockIdx.y >> 4;
    const int r_st = t >> 1, hf = t & 1;
    const int len = load_len(mlen, b);
    const float M = rmax[n0 + r_st], R = rrinv[n0 + r_st];

    f32x4 acc[4][4];
#pragma unroll
    for (int mt = 0; mt < 4; ++mt)
#pragma unroll
        for (int nt = 0; nt < 4; ++nt) acc[mt][nt] = (f32x4)0.f;

    const int s00 = blockIdx.x * sChunks * 32;
    for (int ch = 0; ch < sChunks; ++ch) {
        const int s0 = s00 + (ch << 5);
        if (s0 >= len) {
            // masked chunk: av = 0 exactly; zero contribution to c.
            const long long ga = (long long)(n0 + r_st)*S_ + s0 + hf*16;
            float4 z; z.x = z.y = z.z = z.w = 0.f;
#pragma unroll
            for (int q = 0; q < 4; ++q) *(float4*)&av[ga + q*4] = z;
            continue;
        }
        __syncthreads();
        // stage p (and write av): thread owns 16 s of row r_st
        {
            unsigned short ph[16];
            const long long ga = (long long)(n0 + r_st)*S_ + s0 + hf*16;
#pragma unroll
            for (int q = 0; q < 4; ++q) {
                const float4 v = *(const float4*)&alignI[ga + q*4];
                float4 p;
                p.x = __expf(v.x - M)*R; p.y = __expf(v.y - M)*R;
                p.z = __expf(v.z - M)*R; p.w = __expf(v.w - M)*R;
                *(float4*)&av[ga + q*4] = p;
                ph[q*4+0]=f2bf(p.x); ph[q*4+1]=f2bf(p.y);
                ph[q*4+2]=f2bf(p.z); ph[q*4+3]=f2bf(p.w);
            }
            uint4 w0, w1;
            w0.x=pk2(ph[0],ph[1]);  w0.y=pk2(ph[2],ph[3]);  w0.z=pk2(ph[4],ph[5]);  w0.w=pk2(ph[6],ph[7]);
            w1.x=pk2(ph[8],ph[9]);  w1.y=pk2(ph[10],ph[11]);w1.z=pk2(ph[12],ph[13]);w1.w=pk2(ph[14],ph[15]);
            *(uint4*)&Ph[r_st*40 + hf*16]     = w0;
            *(uint4*)&Ph[r_st*40 + hf*16 + 8] = w1;
        }
        // stage V^T tile: [feat][32 s]
#pragma unroll
        for (int i = 0; i < 2; ++i) {
            const int c = t + (i << 8);
            const int f = c >> 2, sl = c & 3;
            const long long gv = ((long long)(b*128 + f))*S_ + s0 + sl*8;
            *(uint4*)&Vh[f*40 + sl*8] = *(const uint4*)&mbth[gv];
        }
        __syncthreads();
        bf16x8 ph[4];
#pragma unroll
        for (int mt = 0; mt < 4; ++mt)
            ph[mt] = *(const bf16x8*)&Ph[(wm*64 + mt*16 + lr)*40 + g*8];
#pragma unroll
        for (int nt = 0; nt < 4; ++nt) {
            const bf16x8 vh = *(const bf16x8*)&Vh[(wn*64 + nt*16 + lr)*40 + g*8];
#pragma unroll
            for (int mt = 0; mt < 4; ++mt)
                acc[mt][nt] = __builtin_amdgcn_mfma_f32_16x16x32_bf16(ph[mt], vh, acc[mt][nt], 0, 0, 0);
        }
    }

    float* cp = cpart + (long long)blockIdx.x * N_ * 128;
#pragma unroll
    for (int mt = 0; mt < 4; ++mt)
#pragma unroll
        for (int nt = 0; nt < 4; ++nt)
#pragma unroll
            for (int j = 0; j < 4; ++j)
                cp[(long long)(n0 + wm*64 + mt*16 + 4*g + j)*128 + wn*64 + nt*16 + lr]
                    = acc[mt][nt][j];
}

// ---------------------------------------------------------------------------
// K5: combine partial c, attn_h = tanh([c,q] @ W_out^T).
// ---------------------------------------------------------------------------
__global__ __launch_bounds__(256) void combine_proj(
    const float* __restrict__ cpart, const int nSplit,
    const float* __restrict__ query, const float* __restrict__ Wout,
    float* __restrict__ attn)
{
    __shared__ float Cl[32][132];
    __shared__ float Ql[32][132];
    const int n0 = blockIdx.x << 5;
    const int t = threadIdx.x;
    const int r = t >> 3, kq = t & 7;
#pragma unroll
    for (int f = 0; f < 4; ++f) {
        const int k = kq*16 + f*4;
        const long long idx = (long long)(n0 + r) * 128 + k;
        float4 s4 = *(const float4*)&cpart[idx];
        for (int p = 1; p < nSplit; ++p) {
            const float4 v = *(const float4*)&cpart[(long long)p * N_ * 128 + idx];
            s4.x += v.x; s4.y += v.y; s4.z += v.z; s4.w += v.w;
        }
        *(float4*)&Cl[r][k] = s4;
        *(float4*)&Ql[r][k] = *(const float4*)&query[idx];
    }
    __syncthreads();

    const int j = t & 127, rh = t >> 7;
    float acc2[16];
#pragma unroll
    for (int rr = 0; rr < 16; ++rr) acc2[rr] = 0.f;
    const float4* Wrow = (const float4*)&Wout[j * 256];

    for (int k4 = 0; k4 < 32; ++k4) {
        const float4 w = Wrow[k4];
#pragma unroll
        for (int rr = 0; rr < 16; ++rr) {
            const float4 c4 = *(const float4*)&Cl[rh*16 + rr][k4*4];
            acc2[rr] = fmaf(c4.x, w.x, fmaf(c4.y, w.y, fmaf(c4.z, w.z, fmaf(c4.w, w.w, acc2[rr]))));
        }
    }
    for (int k4 = 0; k4 < 32; ++k4) {
        const float4 w = Wrow[32 + k4];
#pragma unroll
        for (int rr = 0; rr < 16; ++rr) {
            const float4 q4 = *(const float4*)&Ql[rh*16 + rr][k4*4];
            acc2[rr] = fmaf(q4.x, w.x, fmaf(q4.y, w.y, fmaf(q4.z, w.z, fmaf(q4.w, w.w, acc2[rr]))));
        }
    }
#pragma unroll
    for (int rr = 0; rr < 16; ++rr)
        attn[(long long)(n0 + rh*16 + rr) * 128 + j] = tanhf(acc2[rr]);
}

// ---------------------------------------------------------------------------
extern "C" void kernel_launch(void* const* d_in, const int* in_sizes, int n_in,
                              void* d_out, int out_size, void* d_ws, size_t ws_size,
                              hipStream_t stream)
{
    const float* query = (const float*)d_in[0];   // [B][T][128]
    const float* mb    = (const float*)d_in[1];   // [B][S][128]
    const int*   mlen  = (const int*)d_in[2];     // [B]
    const float* Win   = (const float*)d_in[3];   // [128][128]
    const float* Wout  = (const float*)d_in[4];   // [128][256]

    float* attn  = (float*)d_out;
    float* av    = attn + (size_t)N_ * D_;
    float* align = av   + (size_t)N_ * S_;

    // workspace layout (ws observed ~2 GB; need ~130 MB at split=8)
    char* p = (char*)d_ws;
    float* rmax  = (float*)p;                 p += (size_t)N_ * 4;
    float* rrinv = (float*)p;                 p += (size_t)N_ * 4;
    float* pmax  = (float*)p;                 p += (size_t)NTILE_ * N_ * 4;
    float* psum  = (float*)p;                 p += (size_t)NTILE_ * N_ * 4;
    float* ht    = (float*)p;                 p += (size_t)N_ * D_ * 4;
    unsigned short* hth  = (unsigned short*)p; p += (size_t)N_ * D_ * 2;
    unsigned short* htl  = (unsigned short*)p; p += (size_t)N_ * D_ * 2;
    unsigned short* mbh  = (unsigned short*)p; p += (size_t)B_ * S_ * D_ * 2;
    unsigned short* mbl  = (unsigned short*)p; p += (size_t)B_ * S_ * D_ * 2;
    unsigned short* mbth = (unsigned short*)p; p += (size_t)B_ * S_ * D_ * 2;
    const size_t usedBase = (size_t)(p - (char*)d_ws);
    const size_t matB = (size_t)N_ * D_ * 4;

    int split;
    float* cpart;
    if (ws_size >= usedBase + 8*matB)      { split = 8; cpart = (float*)p; }
    else if (ws_size >= usedBase + 4*matB) { split = 4; cpart = (float*)p; }
    else if (ws_size >= usedBase + 2*matB) { split = 2; cpart = (float*)p; }
    else if (ws_size >= usedBase + matB)   { split = 1; cpart = (float*)p; }
    else                                   { split = 1; cpart = attn; } // K5 reads own rows then writes

    // K0: mb bf16 splits (row-major hi/lo + transposed hi)
    prep_mb<<<dim3(S_/64, 2, B_), 256, 0, stream>>>(mb, mbh, mbl, mbth);
    // K1: h_t fp32
    ht_gemm<<<dim3(1, N_/128), 256, 0, stream>>>(query, Win, ht);
    // K1b: h_t -> bf16 hi/lo
    split_bf16<<<(N_*D_/4)/256, 256, 0, stream>>>(ht, hth, htl, N_*D_/4);
    // K2: align (masked) + softmax partials
    qk_mfma<<<dim3(S_/128, N_/128), 256, 0, stream>>>(
        hth, htl, mbh, mbl, align, mlen, pmax, psum);
    // K3: merge stats
    merge_stats<<<N_/256, 256, 0, stream>>>(pmax, psum, rmax, rrinv);
    // K4: align_vectors + partial c (1-term, split-8)
    pv_mfma<<<dim3(split, N_/128), 256, 0, stream>>>(
        align, mbth, rmax, rrinv, mlen, av, cpart, (S_/32)/split);
    // K5: combine + output projection
    combine_proj<<<N_/32, 256, 0, stream>>>(cpart, split, query, Wout, attn);
}